// Round 1
// baseline (2985.435 us; speedup 1.0000x reference)
//
#include <hip/hip_runtime.h>
#include <cstdint>
#include <cstdio>
#include <cstring>

// ===========================================================================
// Host-side replication of numpy default_rng(0) REL selection.
// REL is NOT a kernel input; the reference builds it with
// np.random.default_rng(0).choice(len(combos), 3, replace=False) per group.
// We replicate SeedSequence -> PCG64 (XSL-RR 128/64, step-then-output) ->
// Generator.choice (Floyd's algorithm + Lemire-32 bounded draws + shuffle).
// ===========================================================================
namespace nprng {

struct Pcg64 {
  __uint128_t state, inc;
  bool has_uint32;
  uint32_t uinteger;
  static __uint128_t mult() {
    return (((__uint128_t)0x2360ed051fc65da4ULL) << 64) | 0x4385df649fccf645ULL;
  }
  void step() { state = state * mult() + inc; }
  uint64_t next64() {
    step();
    uint64_t hi = (uint64_t)(state >> 64), lo = (uint64_t)state;
    uint32_t rot = (uint32_t)(state >> 122);
    uint64_t x = hi ^ lo;
    return (x >> rot) | (x << ((64u - rot) & 63u));
  }
  uint32_t next32() {
    if (has_uint32) { has_uint32 = false; return uinteger; }
    uint64_t v = next64();
    has_uint32 = true;
    uinteger = (uint32_t)(v >> 32);
    return (uint32_t)v;
  }
};

static void make_default_rng0(Pcg64& g) {
  const uint32_t INIT_A = 0x43b0d7e5u, MULT_A = 0x931e8875u;
  const uint32_t INIT_B = 0x8b51f9ddu, MULT_B = 0x58f38dedu;
  const uint32_t MIX_L = 0xca01f9ddu, MIX_R = 0x4973f715u;
  uint32_t pool[4];
  uint32_t hc = INIT_A;
  auto hashmix = [&](uint32_t v) -> uint32_t {
    v ^= hc; hc *= MULT_A; v *= hc; v ^= v >> 16; return v;
  };
  auto mix = [&](uint32_t x, uint32_t y) -> uint32_t {
    uint32_t r = x * MIX_L - y * MIX_R; r ^= r >> 16; return r;
  };
  // assembled entropy for SeedSequence(0) is [0u]
  for (int i = 0; i < 4; ++i) pool[i] = hashmix(i < 1 ? 0u : 0u);
  for (int s = 0; s < 4; ++s)
    for (int d = 0; d < 4; ++d)
      if (s != d) pool[d] = mix(pool[d], hashmix(pool[s]));
  // generate_state(4, uint64) -> 8 uint32 words
  uint32_t hb = INIT_B;
  uint32_t w[8];
  for (int i = 0; i < 8; ++i) {
    uint32_t dv = pool[i & 3];
    dv ^= hb; hb *= MULT_B; dv *= hb; dv ^= dv >> 16;
    w[i] = dv;
  }
  uint64_t v64[4];
  for (int i = 0; i < 4; ++i) v64[i] = (uint64_t)w[2 * i] | ((uint64_t)w[2 * i + 1] << 32);
  __uint128_t initstate = (((__uint128_t)v64[0]) << 64) | v64[1];
  __uint128_t initseq   = (((__uint128_t)v64[2]) << 64) | v64[3];
  g.inc = (initseq << 1) | 1;
  g.state = 0; g.has_uint32 = false; g.uinteger = 0;
  g.step();
  g.state += initstate;
  g.step();
}

// numpy buffered_bounded_lemire_uint32; rng is the INCLUSIVE max.
static uint32_t lemire32(Pcg64& g, uint32_t rng) {
  if (rng == 0) return 0;
  const uint32_t rng_excl = rng + 1u;
  uint64_t m = (uint64_t)g.next32() * (uint64_t)rng_excl;
  uint32_t leftover = (uint32_t)m;
  if (leftover < rng_excl) {
    const uint32_t threshold = (0xFFFFFFFFu - rng) % rng_excl;
    while (leftover < threshold) {
      m = (uint64_t)g.next32() * (uint64_t)rng_excl;
      leftover = (uint32_t)m;
    }
  }
  return (uint32_t)(m >> 32);
}

// Generator.choice(pop, 3, replace=False): Floyd's algorithm (hash set of 4)
// followed by _shuffle_int(3, 1, idx). Order of the result is irrelevant to the
// final math (relations are summed) but stream consumption must match.
static void choice3(Pcg64& g, int pop, int64_t out[3]) {
  uint64_t hset[4] = {~0ull, ~0ull, ~0ull, ~0ull};
  const uint64_t mask = 3;
  for (int j = pop - 3; j < pop; ++j) {
    uint64_t val = (uint64_t)lemire32(g, (uint32_t)j);
    uint64_t loc = val & mask;
    while (hset[loc] != ~0ull && hset[loc] != val) loc = (loc + 1) & mask;
    if (hset[loc] == ~0ull) {
      hset[loc] = val;
      out[j - pop + 3] = (int64_t)val;
    } else {
      loc = (uint64_t)j & mask;
      while (hset[loc] != ~0ull) loc = (loc + 1) & mask;
      hset[loc] = (uint64_t)j;
      out[j - pop + 3] = (int64_t)j;
    }
  }
  for (int i = 2; i >= 1; --i) {
    int j = (int)lemire32(g, (uint32_t)i);
    int64_t t = out[i]; out[i] = out[j]; out[j] = t;
  }
}

} // namespace nprng

// lexicographic combinations of {0..7} choose s
static int all_combos(int s, int combos[80][8]) {
  int c[8];
  for (int i = 0; i < s; ++i) c[i] = i;
  int cnt = 0;
  while (true) {
    for (int i = 0; i < s; ++i) combos[cnt][i] = c[i];
    ++cnt;
    int i = s - 1;
    while (i >= 0 && c[i] == 8 - s + i) --i;
    if (i < 0) break;
    ++c[i];
    for (int j = i + 1; j < s; ++j) c[j] = c[j - 1] + 1;
  }
  return cnt;
}

// ===========================================================================
// Kernels. fp32 SIMT GEMM (no fp32 MFMA on CDNA4): 64x64 tile, KT=32,
// 256 threads, 4x4 micro-tile, LDS stride 68 (float4-aligned, low-conflict).
// ===========================================================================
#define MTILE 64
#define NTILE 64
#define KTILE 32
#define LSTR  68
#define NREL_MAX 19
#define MDIM 4096
#define NB   256

struct G1Args {
  const float* w1[NREL_MAX];
  const float* b1[NREL_MAX];
  unsigned char frames[NREL_MAX][8];
  unsigned char scale[NREL_MAX];
};

struct G2Args {
  const float* w2[NREL_MAX];
  const float* b2[NREL_MAX];
};

__global__ __launch_bounds__(256) void gemm1_kernel(
    const float* __restrict__ x,   // [4096][8][1024]
    float* __restrict__ h1,        // [zc][4096][256]
    G1Args args, int zbase)
{
  const int zl  = blockIdx.z;
  const int rel = zbase + zl;
  const int m0  = blockIdx.x * MTILE;
  const int n0  = blockIdx.y * NTILE;
  const int K   = ((int)args.scale[rel]) << 10;
  const float* __restrict__ w1 = args.w1[rel];

  __shared__ float As[KTILE][LSTR];
  __shared__ float Bs[KTILE][LSTR];

  const int tid = threadIdx.x;
  const int tx = tid & 15, ty = tid >> 4;
  const int lkA = tid & 31, lmA = tid >> 5;   // A loader: k-lane, row-base
  const int lnB = tid & 63, lkB = tid >> 6;   // B loader: col-lane, k-base

  float acc[4][4] = {};

  for (int k0 = 0; k0 < K; k0 += KTILE) {
    const int fr = (int)args.frames[rel][k0 >> 10];
    const float* xp = x + (size_t)m0 * 8192 + (size_t)fr * 1024 + (k0 & 1023) + lkA;
#pragma unroll
    for (int r = 0; r < 8; ++r) {
      float v = xp[(size_t)(lmA + r * 8) * 8192];
      As[lkA][lmA + r * 8] = fmaxf(v, 0.f);   // relu(g)
    }
    const float* wp = w1 + (size_t)(k0 + lkB) * NB + n0 + lnB;
#pragma unroll
    for (int r = 0; r < 8; ++r) {
      Bs[lkB + r * 4][lnB] = wp[(size_t)r * 4 * NB];
    }
    __syncthreads();
#pragma unroll
    for (int k = 0; k < KTILE; ++k) {
      const float4 av = *(const float4*)&As[k][ty << 2];
      const float4 bv = *(const float4*)&Bs[k][tx << 2];
      const float ar[4] = {av.x, av.y, av.z, av.w};
      const float br[4] = {bv.x, bv.y, bv.z, bv.w};
#pragma unroll
      for (int r = 0; r < 4; ++r)
#pragma unroll
        for (int c = 0; c < 4; ++c)
          acc[r][c] = fmaf(ar[r], br[c], acc[r][c]);
    }
    __syncthreads();
  }

  const float* b1p = args.b1[rel] + n0 + (tx << 2);
  const float4 bias = {b1p[0], b1p[1], b1p[2], b1p[3]};
  float* outp = h1 + ((size_t)zl * MDIM + m0 + (ty << 2)) * NB + n0 + (tx << 2);
#pragma unroll
  for (int r = 0; r < 4; ++r) {
    float4 o;
    o.x = fmaxf(acc[r][0] + bias.x, 0.f);
    o.y = fmaxf(acc[r][1] + bias.y, 0.f);
    o.z = fmaxf(acc[r][2] + bias.z, 0.f);
    o.w = fmaxf(acc[r][3] + bias.w, 0.f);
    *(float4*)(outp + (size_t)r * NB) = o;
  }
}

__global__ __launch_bounds__(256) void gemm2_kernel(
    const float* __restrict__ h1,   // [zc][4096][256]
    float* __restrict__ accb,       // [4096][256]
    G2Args args, int zbase, int zcount, int is_first)
{
  const int m0 = blockIdx.x * MTILE;
  const int n0 = blockIdx.y * NTILE;

  __shared__ float As[KTILE][LSTR];
  __shared__ float Bs[KTILE][LSTR];

  const int tid = threadIdx.x;
  const int tx = tid & 15, ty = tid >> 4;
  const int lkA = tid & 31, lmA = tid >> 5;
  const int lnB = tid & 63, lkB = tid >> 6;

  float total[4][4] = {};

  for (int zl = 0; zl < zcount; ++zl) {
    const int rel = zbase + zl;
    const float* __restrict__ w2 = args.w2[rel];
    float acc[4][4] = {};
    for (int k0 = 0; k0 < NB; k0 += KTILE) {
      const float* hp = h1 + ((size_t)zl * MDIM + m0) * NB + k0 + lkA;
#pragma unroll
      for (int r = 0; r < 8; ++r)
        As[lkA][lmA + r * 8] = hp[(size_t)(lmA + r * 8) * NB];
      const float* wp = w2 + (size_t)(k0 + lkB) * NB + n0 + lnB;
#pragma unroll
      for (int r = 0; r < 8; ++r)
        Bs[lkB + r * 4][lnB] = wp[(size_t)r * 4 * NB];
      __syncthreads();
#pragma unroll
      for (int k = 0; k < KTILE; ++k) {
        const float4 av = *(const float4*)&As[k][ty << 2];
        const float4 bv = *(const float4*)&Bs[k][tx << 2];
        const float ar[4] = {av.x, av.y, av.z, av.w};
        const float br[4] = {bv.x, bv.y, bv.z, bv.w};
#pragma unroll
        for (int r = 0; r < 4; ++r)
#pragma unroll
          for (int c = 0; c < 4; ++c)
            acc[r][c] = fmaf(ar[r], br[c], acc[r][c]);
      }
      __syncthreads();
    }
    const float* b2p = args.b2[rel] + n0 + (tx << 2);
    const float b2v[4] = {b2p[0], b2p[1], b2p[2], b2p[3]};
#pragma unroll
    for (int r = 0; r < 4; ++r)
#pragma unroll
      for (int c = 0; c < 4; ++c)
        total[r][c] += fmaxf(acc[r][c] + b2v[c], 0.f);   // relu per relation BEFORE sum
  }

  float* outp = accb + (size_t)(m0 + (ty << 2)) * NB + n0 + (tx << 2);
#pragma unroll
  for (int r = 0; r < 4; ++r) {
    float4 cur;
    if (is_first) { cur.x = cur.y = cur.z = cur.w = 0.f; }
    else          { cur = *(float4*)(outp + (size_t)r * NB); }
    cur.x += total[r][0];
    cur.y += total[r][1];
    cur.z += total[r][2];
    cur.w += total[r][3];
    *(float4*)(outp + (size_t)r * NB) = cur;
  }
}

#define NC 400

__global__ __launch_bounds__(256) void gemm3_kernel(
    const float* __restrict__ accb,  // [4096][256]
    const float* __restrict__ wc,    // [256][400]
    const float* __restrict__ bc,    // [400]
    float* __restrict__ out)         // [4096][400]
{
  const int m0 = blockIdx.x * MTILE;
  const int n0 = blockIdx.y * NTILE;   // up to 448, guarded at 400

  __shared__ float As[KTILE][LSTR];
  __shared__ float Bs[KTILE][LSTR];

  const int tid = threadIdx.x;
  const int tx = tid & 15, ty = tid >> 4;
  const int lkA = tid & 31, lmA = tid >> 5;
  const int lnB = tid & 63, lkB = tid >> 6;

  float acc[4][4] = {};

  for (int k0 = 0; k0 < NB; k0 += KTILE) {
    const float* hp = accb + (size_t)m0 * NB + k0 + lkA;
#pragma unroll
    for (int r = 0; r < 8; ++r)
      As[lkA][lmA + r * 8] = hp[(size_t)(lmA + r * 8) * NB];
    const int col = n0 + lnB;
#pragma unroll
    for (int r = 0; r < 8; ++r) {
      float v = 0.f;
      if (col < NC) v = wc[(size_t)(k0 + lkB + r * 4) * NC + col];
      Bs[lkB + r * 4][lnB] = v;
    }
    __syncthreads();
#pragma unroll
    for (int k = 0; k < KTILE; ++k) {
      const float4 av = *(const float4*)&As[k][ty << 2];
      const float4 bv = *(const float4*)&Bs[k][tx << 2];
      const float ar[4] = {av.x, av.y, av.z, av.w};
      const float br[4] = {bv.x, bv.y, bv.z, bv.w};
#pragma unroll
      for (int r = 0; r < 4; ++r)
#pragma unroll
        for (int c = 0; c < 4; ++c)
          acc[r][c] = fmaf(ar[r], br[c], acc[r][c]);
    }
    __syncthreads();
  }

#pragma unroll
  for (int r = 0; r < 4; ++r) {
    const int row = m0 + (ty << 2) + r;
#pragma unroll
    for (int c = 0; c < 4; ++c) {
      const int col = n0 + (tx << 2) + c;
      if (col < NC)
        out[(size_t)row * NC + col] = fmaxf(acc[r][c] + bc[col], 0.f);
    }
  }
}

// ===========================================================================
extern "C" void kernel_launch(void* const* d_in, const int* in_sizes, int n_in,
                              void* d_out, int out_size, void* d_ws, size_t ws_size,
                              hipStream_t stream) {
  // ---- PCG64 replication self-check (fresh generator; does not touch stream state)
  {
    nprng::Pcg64 chk; nprng::make_default_rng0(chk);
    double r0 = (double)(chk.next64() >> 11) * (1.0 / 9007199254740992.0);
    if (!(r0 > 0.6369616872 && r0 < 0.6369616874)) {
      fprintf(stderr, "[kernel] WARNING: PCG64 self-check failed: %.17g (expected 0.6369616873214543)\n", r0);
    }
  }

  // ---- build REL exactly as the reference does
  int rel_frames[NREL_MAX][8];
  int rel_scale[NREL_MAX];
  int rel_group[NREL_MAX];
  int n_rel = 0;
  // group 0: scale 8, the single full combination (0..7)
  for (int j = 0; j < 8; ++j) rel_frames[0][j] = j;
  rel_scale[0] = 8; rel_group[0] = 0; n_rel = 1;

  nprng::Pcg64 rng; nprng::make_default_rng0(rng);
  for (int gi = 1; gi <= 6; ++gi) {
    const int scale = 8 - gi;                    // SCALES = [8,7,6,5,4,3,2]
    int combos[80][8];
    const int pop = all_combos(scale, combos);   // C(8,scale), lex order
    int64_t idx[3];
    nprng::choice3(rng, pop, idx);
    for (int t = 0; t < 3; ++t) {
      for (int j = 0; j < 8; ++j) rel_frames[n_rel][j] = (j < scale) ? combos[idx[t]][j] : 0;
      rel_scale[n_rel] = scale;
      rel_group[n_rel] = gi;
      ++n_rel;
    }
  }
  // n_rel == 19

  // ---- kernel arg tables
  G1Args g1; G2Args g2;
  memset(&g1, 0, sizeof(g1)); memset(&g2, 0, sizeof(g2));
  for (int r = 0; r < n_rel; ++r) {
    const int gi = rel_group[r];
    g1.w1[r] = (const float*)d_in[1 + 4 * gi];
    g1.b1[r] = (const float*)d_in[2 + 4 * gi];
    g2.w2[r] = (const float*)d_in[3 + 4 * gi];
    g2.b2[r] = (const float*)d_in[4 + 4 * gi];
    for (int j = 0; j < 8; ++j) g1.frames[r][j] = (unsigned char)rel_frames[r][j];
    g1.scale[r] = (unsigned char)rel_scale[r];
  }
  const float* x  = (const float*)d_in[0];
  const float* wc = (const float*)d_in[29];
  const float* bc = (const float*)d_in[30];

  // ---- workspace layout: acc [4096][256] fp32, then h1 [zcap][4096][256]
  const size_t ACC_ELEMS = (size_t)MDIM * NB;
  float* accb = (float*)d_ws;
  float* h1   = (float*)d_ws + ACC_ELEMS;
  size_t avail = ws_size / 4;
  int zcap = 1;
  if (avail > ACC_ELEMS) {
    size_t cap = (avail - ACC_ELEMS) / ACC_ELEMS;
    zcap = (int)(cap < (size_t)n_rel ? cap : (size_t)n_rel);
    if (zcap < 1) zcap = 1;
  } else {
    fprintf(stderr, "[kernel] WARNING: ws_size=%zu too small\n", ws_size);
  }

  // ---- pipeline
  int zbase = 0;
  int first = 1;
  while (zbase < n_rel) {
    const int zc = (n_rel - zbase < zcap) ? (n_rel - zbase) : zcap;
    gemm1_kernel<<<dim3(MDIM / MTILE, NB / NTILE, zc), 256, 0, stream>>>(x, h1, g1, zbase);
    gemm2_kernel<<<dim3(MDIM / MTILE, NB / NTILE), 256, 0, stream>>>(h1, accb, g2, zbase, zc, first);
    first = 0;
    zbase += zc;
  }
  gemm3_kernel<<<dim3(MDIM / MTILE, (NC + NTILE - 1) / NTILE), 256, 0, stream>>>(accb, wc, bc, (float*)d_out);
}

// Round 2
// 587.324 us; speedup vs baseline: 5.0831x; 5.0831x over previous
//
#include <hip/hip_runtime.h>
#include <cstdint>
#include <cstdio>
#include <cstring>

// ===========================================================================
// Host-side replication of numpy default_rng(0) REL selection (verified r1).
// ===========================================================================
namespace nprng {

struct Pcg64 {
  __uint128_t state, inc;
  bool has_uint32;
  uint32_t uinteger;
  static __uint128_t mult() {
    return (((__uint128_t)0x2360ed051fc65da4ULL) << 64) | 0x4385df649fccf645ULL;
  }
  void step() { state = state * mult() + inc; }
  uint64_t next64() {
    step();
    uint64_t hi = (uint64_t)(state >> 64), lo = (uint64_t)state;
    uint32_t rot = (uint32_t)(state >> 122);
    uint64_t x = hi ^ lo;
    return (x >> rot) | (x << ((64u - rot) & 63u));
  }
  uint32_t next32() {
    if (has_uint32) { has_uint32 = false; return uinteger; }
    uint64_t v = next64();
    has_uint32 = true;
    uinteger = (uint32_t)(v >> 32);
    return (uint32_t)v;
  }
};

static void make_default_rng0(Pcg64& g) {
  const uint32_t INIT_A = 0x43b0d7e5u, MULT_A = 0x931e8875u;
  const uint32_t INIT_B = 0x8b51f9ddu, MULT_B = 0x58f38dedu;
  const uint32_t MIX_L = 0xca01f9ddu, MIX_R = 0x4973f715u;
  uint32_t pool[4];
  uint32_t hc = INIT_A;
  auto hashmix = [&](uint32_t v) -> uint32_t {
    v ^= hc; hc *= MULT_A; v *= hc; v ^= v >> 16; return v;
  };
  auto mix = [&](uint32_t x, uint32_t y) -> uint32_t {
    uint32_t r = x * MIX_L - y * MIX_R; r ^= r >> 16; return r;
  };
  for (int i = 0; i < 4; ++i) pool[i] = hashmix(0u);
  for (int s = 0; s < 4; ++s)
    for (int d = 0; d < 4; ++d)
      if (s != d) pool[d] = mix(pool[d], hashmix(pool[s]));
  uint32_t hb = INIT_B;
  uint32_t w[8];
  for (int i = 0; i < 8; ++i) {
    uint32_t dv = pool[i & 3];
    dv ^= hb; hb *= MULT_B; dv *= hb; dv ^= dv >> 16;
    w[i] = dv;
  }
  uint64_t v64[4];
  for (int i = 0; i < 4; ++i) v64[i] = (uint64_t)w[2 * i] | ((uint64_t)w[2 * i + 1] << 32);
  __uint128_t initstate = (((__uint128_t)v64[0]) << 64) | v64[1];
  __uint128_t initseq   = (((__uint128_t)v64[2]) << 64) | v64[3];
  g.inc = (initseq << 1) | 1;
  g.state = 0; g.has_uint32 = false; g.uinteger = 0;
  g.step();
  g.state += initstate;
  g.step();
}

static uint32_t lemire32(Pcg64& g, uint32_t rng) {
  if (rng == 0) return 0;
  const uint32_t rng_excl = rng + 1u;
  uint64_t m = (uint64_t)g.next32() * (uint64_t)rng_excl;
  uint32_t leftover = (uint32_t)m;
  if (leftover < rng_excl) {
    const uint32_t threshold = (0xFFFFFFFFu - rng) % rng_excl;
    while (leftover < threshold) {
      m = (uint64_t)g.next32() * (uint64_t)rng_excl;
      leftover = (uint32_t)m;
    }
  }
  return (uint32_t)(m >> 32);
}

static void choice3(Pcg64& g, int pop, int64_t out[3]) {
  uint64_t hset[4] = {~0ull, ~0ull, ~0ull, ~0ull};
  const uint64_t mask = 3;
  for (int j = pop - 3; j < pop; ++j) {
    uint64_t val = (uint64_t)lemire32(g, (uint32_t)j);
    uint64_t loc = val & mask;
    while (hset[loc] != ~0ull && hset[loc] != val) loc = (loc + 1) & mask;
    if (hset[loc] == ~0ull) {
      hset[loc] = val;
      out[j - pop + 3] = (int64_t)val;
    } else {
      loc = (uint64_t)j & mask;
      while (hset[loc] != ~0ull) loc = (loc + 1) & mask;
      hset[loc] = (uint64_t)j;
      out[j - pop + 3] = (int64_t)j;
    }
  }
  for (int i = 2; i >= 1; --i) {
    int j = (int)lemire32(g, (uint32_t)i);
    int64_t t = out[i]; out[i] = out[j]; out[j] = t;
  }
}

} // namespace nprng

static int all_combos(int s, int combos[80][8]) {
  int c[8];
  for (int i = 0; i < s; ++i) c[i] = i;
  int cnt = 0;
  while (true) {
    for (int i = 0; i < s; ++i) combos[cnt][i] = c[i];
    ++cnt;
    int i = s - 1;
    while (i >= 0 && c[i] == 8 - s + i) --i;
    if (i < 0) break;
    ++c[i];
    for (int j = i + 1; j < s; ++j) c[j] = c[j - 1] + 1;
  }
  return cnt;
}

// ===========================================================================
// Common defs
// ===========================================================================
#define NREL_MAX 19
#define MDIM 4096
#define NB   256
#define NC   400

typedef __attribute__((ext_vector_type(8))) short bf16x8;
typedef __attribute__((ext_vector_type(4))) float f32x4;

__device__ __forceinline__ uint16_t f2bf(float f) {
  uint32_t u = __builtin_bit_cast(uint32_t, f);
  u += 0x7FFFu + ((u >> 16) & 1u);   // RNE
  return (uint16_t)(u >> 16);
}

__device__ __forceinline__ void gload_lds16(const void* g, void* l) {
  __builtin_amdgcn_global_load_lds(
      (const __attribute__((address_space(1))) unsigned int*)g,
      (__attribute__((address_space(3))) unsigned int*)l, 16, 0, 0);
}

// ===========================================================================
// FAST PATH: precompute bf16 operands in ws, MFMA GEMM1/GEMM2.
// ===========================================================================

// xr[b][f][d] = bf16(relu(x[b][f][d])); n8 = total/8
__global__ __launch_bounds__(256) void conv_x_kernel(
    const float* __restrict__ x, uint16_t* __restrict__ xr, int n8)
{
  int i = blockIdx.x * 256 + threadIdx.x;
  const int stride = gridDim.x * 256;
  for (; i < n8; i += stride) {
    const float4 a = ((const float4*)x)[2 * i];
    const float4 b = ((const float4*)x)[2 * i + 1];
    uint32_t p0 = (uint32_t)f2bf(fmaxf(a.x, 0.f)) | ((uint32_t)f2bf(fmaxf(a.y, 0.f)) << 16);
    uint32_t p1 = (uint32_t)f2bf(fmaxf(a.z, 0.f)) | ((uint32_t)f2bf(fmaxf(a.w, 0.f)) << 16);
    uint32_t p2 = (uint32_t)f2bf(fmaxf(b.x, 0.f)) | ((uint32_t)f2bf(fmaxf(b.y, 0.f)) << 16);
    uint32_t p3 = (uint32_t)f2bf(fmaxf(b.z, 0.f)) | ((uint32_t)f2bf(fmaxf(b.w, 0.f)) << 16);
    ((uint4*)xr)[i] = make_uint4(p0, p1, p2, p3);
  }
}

// dst_g[n][k] = bf16(src_g[k][n]); src is [K_g][256] fp32. 32x32 LDS transpose.
struct ConvTArgs { const float* src[7]; uint16_t* dst[7]; int K[7]; };

__global__ __launch_bounds__(256) void conv_wT_kernel(ConvTArgs a) {
  const int g = blockIdx.z;
  const int K = a.K[g];
  const int k0 = blockIdx.x * 32;
  if (k0 >= K) return;
  const int n0 = blockIdx.y * 32;
  __shared__ float t[32][33];
  const int tr = threadIdx.x >> 5;   // 0..7
  const int tc = threadIdx.x & 31;
  const float* src = a.src[g];
#pragma unroll
  for (int i = 0; i < 4; ++i) {
    const int r = tr + i * 8;
    t[r][tc] = src[(size_t)(k0 + r) * NB + n0 + tc];
  }
  __syncthreads();
  uint16_t* dst = a.dst[g];
#pragma unroll
  for (int i = 0; i < 4; ++i) {
    const int r = tr + i * 8;
    dst[(size_t)(n0 + r) * K + k0 + tc] = f2bf(t[tc][r]);
  }
}

struct G1F {
  const uint16_t* w1T[NREL_MAX];
  const float*    b1[NREL_MAX];
  unsigned char frames[NREL_MAX][8];
  unsigned char scale[NREL_MAX];
};
struct G2F {
  const uint16_t* w2T[NREL_MAX];
  const float*    b2[NREL_MAX];
};

// GEMM1: h1[zl][m][n] = bf16(relu( relu(g)·w1 + b1 )), per relation.
// m97 structure: 128x128 tile, BK=32, 4 waves (2x2), wave=64x64 (4x4 frags),
// global_load_lds width 16, single-buffered LDS.
__global__ __launch_bounds__(256) void gemm1_mfma(
    const uint16_t* __restrict__ xr,   // [4096][8][1024] bf16 (relu applied)
    uint16_t* __restrict__ h1,         // [zc][4096][256] bf16
    G1F args, int zbase)
{
  __shared__ __align__(16) uint16_t sA[128 * 32];  // [row][k] 64B rows
  __shared__ __align__(16) uint16_t sB[128 * 32];  // [n][k]
  const int zl  = blockIdx.z;
  const int rel = zbase + zl;
  const int m0  = blockIdx.x * 128;
  const int n0  = blockIdx.y * 128;
  const int scale = (int)args.scale[rel];
  const uint16_t* __restrict__ w1T = args.w1T[rel];
  const int K = scale << 10;

  const int tid  = threadIdx.x;
  const int l    = tid & 63;
  const int w    = tid >> 6;
  const int wm   = w >> 1, wn = w & 1;
  const int lcol = l & 15;
  const int kgrp = (l >> 4) << 3;          // 0,8,16,24 (elem)
  const int srow = tid >> 2;               // staging row 0..63
  const int sko  = (tid & 3) << 3;         // staging k elem offset
  const int ldsoff = (tid >> 6) << 10;     // w*1024 bytes (wave-uniform)

  f32x4 acc[4][4] = {};

  const uint16_t* xbA  = xr + (size_t)(m0 + srow) * 8192 + sko;
  const uint16_t* xbA2 = xr + (size_t)(m0 + 64 + srow) * 8192 + sko;
  const uint16_t* wbB  = w1T + (size_t)(n0 + srow) * K + sko;
  const uint16_t* wbB2 = w1T + (size_t)(n0 + 64 + srow) * K + sko;

  for (int fi = 0; fi < scale; ++fi) {
    const int fr = (int)args.frames[rel][fi];
    const uint16_t* xa  = xbA  + fr * 1024;
    const uint16_t* xa2 = xbA2 + fr * 1024;
    const uint16_t* wb  = wbB  + (fi << 10);
    const uint16_t* wb2 = wbB2 + (fi << 10);
    for (int kc = 0; kc < 1024; kc += 32) {
      gload_lds16(xa  + kc, (char*)sA + ldsoff);
      gload_lds16(xa2 + kc, (char*)sA + 4096 + ldsoff);
      gload_lds16(wb  + kc, (char*)sB + ldsoff);
      gload_lds16(wb2 + kc, (char*)sB + 4096 + ldsoff);
      asm volatile("s_waitcnt vmcnt(0)" ::: "memory");
      __syncthreads();
      bf16x8 af[4], bv[4];
#pragma unroll
      for (int i = 0; i < 4; ++i) {
        af[i] = *(const bf16x8*)((const char*)sA + (((wm << 6) + (i << 4) + lcol) << 6) + (kgrp << 1));
        bv[i] = *(const bf16x8*)((const char*)sB + (((wn << 6) + (i << 4) + lcol) << 6) + (kgrp << 1));
      }
#pragma unroll
      for (int i = 0; i < 4; ++i)
#pragma unroll
        for (int j = 0; j < 4; ++j)
          acc[i][j] = __builtin_amdgcn_mfma_f32_16x16x32_bf16(af[i], bv[j], acc[i][j], 0, 0, 0);
      __syncthreads();
    }
  }

  const float* b1 = args.b1[rel];
  float b1v[4];
#pragma unroll
  for (int j = 0; j < 4; ++j) b1v[j] = b1[n0 + (wn << 6) + (j << 4) + lcol];
  const int orow = (l >> 4) << 2;
#pragma unroll
  for (int i = 0; i < 4; ++i) {
#pragma unroll
    for (int q = 0; q < 4; ++q) {
      const int row = m0 + (wm << 6) + (i << 4) + orow + q;
      uint16_t* hp = h1 + ((size_t)zl * MDIM + row) * NB + n0 + (wn << 6) + lcol;
#pragma unroll
      for (int j = 0; j < 4; ++j)
        hp[j << 4] = f2bf(fmaxf(acc[i][j][q] + b1v[j], 0.f));
    }
  }
}

// GEMM2: accb[m][n] (+)= sum_rel relu( h1_rel·w2 + b2 ). 64x64 tile, BK=32,
// 4 waves (2x2), wave=32x32 (2x2 frags).
__global__ __launch_bounds__(256) void gemm2_mfma(
    const uint16_t* __restrict__ h1, float* __restrict__ accb,
    G2F args, int zbase, int zcount, int is_first)
{
  __shared__ __align__(16) uint16_t sA[64 * 32];
  __shared__ __align__(16) uint16_t sB[64 * 32];
  const int m0 = blockIdx.x * 64;
  const int n0 = blockIdx.y * 64;
  const int tid  = threadIdx.x;
  const int l    = tid & 63;
  const int w    = tid >> 6;
  const int wm   = w >> 1, wn = w & 1;
  const int lcol = l & 15;
  const int kgrp = (l >> 4) << 3;
  const int srow = tid >> 2;
  const int sko  = (tid & 3) << 3;
  const int ldsoff = (tid >> 6) << 10;

  float tot[2][2][4] = {};

  for (int zl = 0; zl < zcount; ++zl) {
    const int rel = zbase + zl;
    const uint16_t* __restrict__ w2T = args.w2T[rel];
    const uint16_t* ha = h1 + ((size_t)zl * MDIM + m0 + srow) * NB + sko;
    const uint16_t* wb = w2T + (size_t)(n0 + srow) * NB + sko;
    f32x4 acc[2][2] = {};
    for (int k0 = 0; k0 < NB; k0 += 32) {
      gload_lds16(ha + k0, (char*)sA + ldsoff);
      gload_lds16(wb + k0, (char*)sB + ldsoff);
      asm volatile("s_waitcnt vmcnt(0)" ::: "memory");
      __syncthreads();
      bf16x8 af[2], bv[2];
#pragma unroll
      for (int i = 0; i < 2; ++i) {
        af[i] = *(const bf16x8*)((const char*)sA + (((wm << 5) + (i << 4) + lcol) << 6) + (kgrp << 1));
        bv[i] = *(const bf16x8*)((const char*)sB + (((wn << 5) + (i << 4) + lcol) << 6) + (kgrp << 1));
      }
#pragma unroll
      for (int i = 0; i < 2; ++i)
#pragma unroll
        for (int j = 0; j < 2; ++j)
          acc[i][j] = __builtin_amdgcn_mfma_f32_16x16x32_bf16(af[i], bv[j], acc[i][j], 0, 0, 0);
      __syncthreads();
    }
    const float* b2 = args.b2[rel];
    float b2v[2];
#pragma unroll
    for (int j = 0; j < 2; ++j) b2v[j] = b2[n0 + (wn << 5) + (j << 4) + lcol];
#pragma unroll
    for (int i = 0; i < 2; ++i)
#pragma unroll
      for (int j = 0; j < 2; ++j)
#pragma unroll
        for (int q = 0; q < 4; ++q)
          tot[i][j][q] += fmaxf(acc[i][j][q] + b2v[j], 0.f);
  }

  const int orow = (l >> 4) << 2;
#pragma unroll
  for (int i = 0; i < 2; ++i) {
#pragma unroll
    for (int q = 0; q < 4; ++q) {
      const int row = m0 + (wm << 5) + (i << 4) + orow + q;
      float* ap = accb + (size_t)row * NB + n0 + (wn << 5) + lcol;
#pragma unroll
      for (int j = 0; j < 2; ++j) {
        float v = tot[i][j][q];
        if (!is_first) v += ap[j << 4];
        ap[j << 4] = v;
      }
    }
  }
}

// ===========================================================================
// FALLBACK PATH (round-1 fp32 SIMT, known-good) + shared GEMM3
// ===========================================================================
#define MTILE 64
#define NTILE 64
#define KTILE 32
#define LSTR  68

struct G1Args {
  const float* w1[NREL_MAX];
  const float* b1[NREL_MAX];
  unsigned char frames[NREL_MAX][8];
  unsigned char scale[NREL_MAX];
};
struct G2Args {
  const float* w2[NREL_MAX];
  const float* b2[NREL_MAX];
};

__global__ __launch_bounds__(256) void gemm1_kernel(
    const float* __restrict__ x, float* __restrict__ h1, G1Args args, int zbase)
{
  const int zl  = blockIdx.z;
  const int rel = zbase + zl;
  const int m0  = blockIdx.x * MTILE;
  const int n0  = blockIdx.y * NTILE;
  const int K   = ((int)args.scale[rel]) << 10;
  const float* __restrict__ w1 = args.w1[rel];

  __shared__ float As[KTILE][LSTR];
  __shared__ float Bs[KTILE][LSTR];

  const int tid = threadIdx.x;
  const int tx = tid & 15, ty = tid >> 4;
  const int lkA = tid & 31, lmA = tid >> 5;
  const int lnB = tid & 63, lkB = tid >> 6;

  float acc[4][4] = {};

  for (int k0 = 0; k0 < K; k0 += KTILE) {
    const int fr = (int)args.frames[rel][k0 >> 10];
    const float* xp = x + (size_t)m0 * 8192 + (size_t)fr * 1024 + (k0 & 1023) + lkA;
#pragma unroll
    for (int r = 0; r < 8; ++r) {
      float v = xp[(size_t)(lmA + r * 8) * 8192];
      As[lkA][lmA + r * 8] = fmaxf(v, 0.f);
    }
    const float* wp = w1 + (size_t)(k0 + lkB) * NB + n0 + lnB;
#pragma unroll
    for (int r = 0; r < 8; ++r)
      Bs[lkB + r * 4][lnB] = wp[(size_t)r * 4 * NB];
    __syncthreads();
#pragma unroll
    for (int k = 0; k < KTILE; ++k) {
      const float4 av = *(const float4*)&As[k][ty << 2];
      const float4 bvv = *(const float4*)&Bs[k][tx << 2];
      const float ar[4] = {av.x, av.y, av.z, av.w};
      const float br[4] = {bvv.x, bvv.y, bvv.z, bvv.w};
#pragma unroll
      for (int r = 0; r < 4; ++r)
#pragma unroll
        for (int c = 0; c < 4; ++c)
          acc[r][c] = fmaf(ar[r], br[c], acc[r][c]);
    }
    __syncthreads();
  }

  const float* b1p = args.b1[rel] + n0 + (tx << 2);
  const float4 bias = {b1p[0], b1p[1], b1p[2], b1p[3]};
  float* outp = h1 + ((size_t)zl * MDIM + m0 + (ty << 2)) * NB + n0 + (tx << 2);
#pragma unroll
  for (int r = 0; r < 4; ++r) {
    float4 o;
    o.x = fmaxf(acc[r][0] + bias.x, 0.f);
    o.y = fmaxf(acc[r][1] + bias.y, 0.f);
    o.z = fmaxf(acc[r][2] + bias.z, 0.f);
    o.w = fmaxf(acc[r][3] + bias.w, 0.f);
    *(float4*)(outp + (size_t)r * NB) = o;
  }
}

__global__ __launch_bounds__(256) void gemm2_kernel(
    const float* __restrict__ h1, float* __restrict__ accb,
    G2Args args, int zbase, int zcount, int is_first)
{
  const int m0 = blockIdx.x * MTILE;
  const int n0 = blockIdx.y * NTILE;

  __shared__ float As[KTILE][LSTR];
  __shared__ float Bs[KTILE][LSTR];

  const int tid = threadIdx.x;
  const int tx = tid & 15, ty = tid >> 4;
  const int lkA = tid & 31, lmA = tid >> 5;
  const int lnB = tid & 63, lkB = tid >> 6;

  float total[4][4] = {};

  for (int zl = 0; zl < zcount; ++zl) {
    const int rel = zbase + zl;
    const float* __restrict__ w2 = args.w2[rel];
    float acc[4][4] = {};
    for (int k0 = 0; k0 < NB; k0 += KTILE) {
      const float* hp = h1 + ((size_t)zl * MDIM + m0) * NB + k0 + lkA;
#pragma unroll
      for (int r = 0; r < 8; ++r)
        As[lkA][lmA + r * 8] = hp[(size_t)(lmA + r * 8) * NB];
      const float* wp = w2 + (size_t)(k0 + lkB) * NB + n0 + lnB;
#pragma unroll
      for (int r = 0; r < 8; ++r)
        Bs[lkB + r * 4][lnB] = wp[(size_t)r * 4 * NB];
      __syncthreads();
#pragma unroll
      for (int k = 0; k < KTILE; ++k) {
        const float4 av = *(const float4*)&As[k][ty << 2];
        const float4 bvv = *(const float4*)&Bs[k][tx << 2];
        const float ar[4] = {av.x, av.y, av.z, av.w};
        const float br[4] = {bvv.x, bvv.y, bvv.z, bvv.w};
#pragma unroll
        for (int r = 0; r < 4; ++r)
#pragma unroll
          for (int c = 0; c < 4; ++c)
            acc[r][c] = fmaf(ar[r], br[c], acc[r][c]);
      }
      __syncthreads();
    }
    const float* b2p = args.b2[rel] + n0 + (tx << 2);
    const float b2v[4] = {b2p[0], b2p[1], b2p[2], b2p[3]};
#pragma unroll
    for (int r = 0; r < 4; ++r)
#pragma unroll
      for (int c = 0; c < 4; ++c)
        total[r][c] += fmaxf(acc[r][c] + b2v[c], 0.f);
  }

  float* outp = accb + (size_t)(m0 + (ty << 2)) * NB + n0 + (tx << 2);
#pragma unroll
  for (int r = 0; r < 4; ++r) {
    float4 cur;
    if (is_first) { cur.x = cur.y = cur.z = cur.w = 0.f; }
    else          { cur = *(float4*)(outp + (size_t)r * NB); }
    cur.x += total[r][0];
    cur.y += total[r][1];
    cur.z += total[r][2];
    cur.w += total[r][3];
    *(float4*)(outp + (size_t)r * NB) = cur;
  }
}

__global__ __launch_bounds__(256) void gemm3_kernel(
    const float* __restrict__ accb, const float* __restrict__ wc,
    const float* __restrict__ bc, float* __restrict__ out)
{
  const int m0 = blockIdx.x * MTILE;
  const int n0 = blockIdx.y * NTILE;

  __shared__ float As[KTILE][LSTR];
  __shared__ float Bs[KTILE][LSTR];

  const int tid = threadIdx.x;
  const int tx = tid & 15, ty = tid >> 4;
  const int lkA = tid & 31, lmA = tid >> 5;
  const int lnB = tid & 63, lkB = tid >> 6;

  float acc[4][4] = {};

  for (int k0 = 0; k0 < NB; k0 += KTILE) {
    const float* hp = accb + (size_t)m0 * NB + k0 + lkA;
#pragma unroll
    for (int r = 0; r < 8; ++r)
      As[lkA][lmA + r * 8] = hp[(size_t)(lmA + r * 8) * NB];
    const int col = n0 + lnB;
#pragma unroll
    for (int r = 0; r < 8; ++r) {
      float v = 0.f;
      if (col < NC) v = wc[(size_t)(k0 + lkB + r * 4) * NC + col];
      Bs[lkB + r * 4][lnB] = v;
    }
    __syncthreads();
#pragma unroll
    for (int k = 0; k < KTILE; ++k) {
      const float4 av = *(const float4*)&As[k][ty << 2];
      const float4 bvv = *(const float4*)&Bs[k][tx << 2];
      const float ar[4] = {av.x, av.y, av.z, av.w};
      const float br[4] = {bvv.x, bvv.y, bvv.z, bvv.w};
#pragma unroll
      for (int r = 0; r < 4; ++r)
#pragma unroll
        for (int c = 0; c < 4; ++c)
          acc[r][c] = fmaf(ar[r], br[c], acc[r][c]);
    }
    __syncthreads();
  }

#pragma unroll
  for (int r = 0; r < 4; ++r) {
    const int row = m0 + (ty << 2) + r;
#pragma unroll
    for (int c = 0; c < 4; ++c) {
      const int col = n0 + (tx << 2) + c;
      if (col < NC)
        out[(size_t)row * NC + col] = fmaxf(acc[r][c] + bc[col], 0.f);
    }
  }
}

// ===========================================================================
extern "C" void kernel_launch(void* const* d_in, const int* in_sizes, int n_in,
                              void* d_out, int out_size, void* d_ws, size_t ws_size,
                              hipStream_t stream) {
  {
    nprng::Pcg64 chk; nprng::make_default_rng0(chk);
    double r0 = (double)(chk.next64() >> 11) * (1.0 / 9007199254740992.0);
    if (!(r0 > 0.6369616872 && r0 < 0.6369616874))
      fprintf(stderr, "[kernel] WARNING: PCG64 self-check failed: %.17g\n", r0);
  }

  // ---- build REL
  int rel_frames[NREL_MAX][8];
  int rel_scale[NREL_MAX];
  int rel_group[NREL_MAX];
  int n_rel = 0;
  for (int j = 0; j < 8; ++j) rel_frames[0][j] = j;
  rel_scale[0] = 8; rel_group[0] = 0; n_rel = 1;

  nprng::Pcg64 rng; nprng::make_default_rng0(rng);
  for (int gi = 1; gi <= 6; ++gi) {
    const int scale = 8 - gi;
    int combos[80][8];
    const int pop = all_combos(scale, combos);
    int64_t idx[3];
    nprng::choice3(rng, pop, idx);
    for (int t = 0; t < 3; ++t) {
      for (int j = 0; j < 8; ++j) rel_frames[n_rel][j] = (j < scale) ? combos[idx[t]][j] : 0;
      rel_scale[n_rel] = scale;
      rel_group[n_rel] = gi;
      ++n_rel;
    }
  }

  const float* x  = (const float*)d_in[0];
  const float* wc = (const float*)d_in[29];
  const float* bc = (const float*)d_in[30];

  // ---- ws layout (fast path)
  const size_t ACC_B   = (size_t)MDIM * NB * 4;                 // 4 MiB fp32
  const size_t XR_B    = (size_t)MDIM * 8 * 1024 * 2;           // 64 MiB bf16
  const size_t W1T_B   = (size_t)35 * 1024 * NB * 2;            // 17.5 MiB
  const size_t W2T_B   = (size_t)7 * NB * NB * 2;               // 0.875 MiB
  const size_t H1REL_B = (size_t)MDIM * NB * 2;                 // 2 MiB / rel
  const size_t off_acc = 0;
  const size_t off_xr  = off_acc + ACC_B;
  const size_t off_w1t = off_xr + XR_B;
  const size_t off_w2t = off_w1t + W1T_B;
  const size_t off_h1  = off_w2t + W2T_B;
  const size_t need_fast = off_h1 + H1REL_B;

  float* accb = (float*)((char*)d_ws + off_acc);

  if (ws_size >= need_fast) {
    // ---------------- FAST PATH (bf16 MFMA) ----------------
    uint16_t* xr = (uint16_t*)((char*)d_ws + off_xr);
    uint16_t* h1 = (uint16_t*)((char*)d_ws + off_h1);
    int zcap = (int)((ws_size - off_h1) / H1REL_B);
    if (zcap > n_rel) zcap = n_rel;

    // per-group w1T offsets (groups 0..6, scale 8..2)
    uint16_t* w1t_g[7];
    size_t o = off_w1t;
    for (int g = 0; g < 7; ++g) {
      w1t_g[g] = (uint16_t*)((char*)d_ws + o);
      o += (size_t)(8 - g) * 1024 * NB * 2;
    }
    uint16_t* w2t_g[7];
    for (int g = 0; g < 7; ++g)
      w2t_g[g] = (uint16_t*)((char*)d_ws + off_w2t + (size_t)g * NB * NB * 2);

    // conversions
    conv_x_kernel<<<4096, 256, 0, stream>>>(x, xr, (int)(MDIM * 8 * 1024 / 8));
    ConvTArgs c1, c2;
    for (int g = 0; g < 7; ++g) {
      c1.src[g] = (const float*)d_in[1 + 4 * g];
      c1.dst[g] = w1t_g[g];
      c1.K[g]   = (8 - g) * 1024;
      c2.src[g] = (const float*)d_in[3 + 4 * g];
      c2.dst[g] = w2t_g[g];
      c2.K[g]   = NB;
    }
    conv_wT_kernel<<<dim3(256, 8, 7), 256, 0, stream>>>(c1);
    conv_wT_kernel<<<dim3(8, 8, 7), 256, 0, stream>>>(c2);

    // arg tables
    G1F g1; G2F g2;
    memset(&g1, 0, sizeof(g1)); memset(&g2, 0, sizeof(g2));
    for (int r = 0; r < n_rel; ++r) {
      const int gi = rel_group[r];
      g1.w1T[r] = w1t_g[gi];
      g1.b1[r]  = (const float*)d_in[2 + 4 * gi];
      g2.w2T[r] = w2t_g[gi];
      g2.b2[r]  = (const float*)d_in[4 + 4 * gi];
      for (int j = 0; j < 8; ++j) g1.frames[r][j] = (unsigned char)rel_frames[r][j];
      g1.scale[r] = (unsigned char)rel_scale[r];
    }

    int zbase = 0, first = 1;
    while (zbase < n_rel) {
      const int zc = (n_rel - zbase < zcap) ? (n_rel - zbase) : zcap;
      gemm1_mfma<<<dim3(MDIM / 128, NB / 128, zc), 256, 0, stream>>>(xr, h1, g1, zbase);
      gemm2_mfma<<<dim3(MDIM / 64, NB / 64), 256, 0, stream>>>(h1, accb, g2, zbase, zc, first);
      first = 0;
      zbase += zc;
    }
  } else {
    // ---------------- FALLBACK (fp32 SIMT, round-1) ----------------
    G1Args g1; G2Args g2;
    memset(&g1, 0, sizeof(g1)); memset(&g2, 0, sizeof(g2));
    for (int r = 0; r < n_rel; ++r) {
      const int gi = rel_group[r];
      g1.w1[r] = (const float*)d_in[1 + 4 * gi];
      g1.b1[r] = (const float*)d_in[2 + 4 * gi];
      g2.w2[r] = (const float*)d_in[3 + 4 * gi];
      g2.b2[r] = (const float*)d_in[4 + 4 * gi];
      for (int j = 0; j < 8; ++j) g1.frames[r][j] = (unsigned char)rel_frames[r][j];
      g1.scale[r] = (unsigned char)rel_scale[r];
    }
    const size_t ACC_ELEMS = (size_t)MDIM * NB;
    float* h1f = (float*)d_ws + ACC_ELEMS;
    size_t avail = ws_size / 4;
    int zcap = 1;
    if (avail > ACC_ELEMS) {
      size_t cap = (avail - ACC_ELEMS) / ACC_ELEMS;
      zcap = (int)(cap < (size_t)n_rel ? cap : (size_t)n_rel);
      if (zcap < 1) zcap = 1;
    }
    int zbase = 0, first = 1;
    while (zbase < n_rel) {
      const int zc = (n_rel - zbase < zcap) ? (n_rel - zbase) : zcap;
      gemm1_kernel<<<dim3(MDIM / MTILE, NB / NTILE, zc), 256, 0, stream>>>(x, h1f, g1, zbase);
      gemm2_kernel<<<dim3(MDIM / MTILE, NB / NTILE), 256, 0, stream>>>(h1f, accb, g2, zbase, zc, first);
      first = 0;
      zbase += zc;
    }
  }

  gemm3_kernel<<<dim3(MDIM / MTILE, (NC + NTILE - 1) / NTILE), 256, 0, stream>>>(
      accb, wc, bc, (float*)d_out);
}

// Round 4
// 582.209 us; speedup vs baseline: 5.1278x; 1.0088x over previous
//
#include <hip/hip_runtime.h>
#include <cstdint>
#include <cstdio>
#include <cstring>

// ===========================================================================
// Host-side replication of numpy default_rng(0) REL selection (verified r1/r2).
// ===========================================================================
namespace nprng {

struct Pcg64 {
  __uint128_t state, inc;
  bool has_uint32;
  uint32_t uinteger;
  static __uint128_t mult() {
    return (((__uint128_t)0x2360ed051fc65da4ULL) << 64) | 0x4385df649fccf645ULL;
  }
  void step() { state = state * mult() + inc; }
  uint64_t next64() {
    step();
    uint64_t hi = (uint64_t)(state >> 64), lo = (uint64_t)state;
    uint32_t rot = (uint32_t)(state >> 122);
    uint64_t x = hi ^ lo;
    return (x >> rot) | (x << ((64u - rot) & 63u));
  }
  uint32_t next32() {
    if (has_uint32) { has_uint32 = false; return uinteger; }
    uint64_t v = next64();
    has_uint32 = true;
    uinteger = (uint32_t)(v >> 32);
    return (uint32_t)v;
  }
};

static void make_default_rng0(Pcg64& g) {
  const uint32_t INIT_A = 0x43b0d7e5u, MULT_A = 0x931e8875u;
  const uint32_t INIT_B = 0x8b51f9ddu, MULT_B = 0x58f38dedu;
  const uint32_t MIX_L = 0xca01f9ddu, MIX_R = 0x4973f715u;
  uint32_t pool[4];
  uint32_t hc = INIT_A;
  auto hashmix = [&](uint32_t v) -> uint32_t {
    v ^= hc; hc *= MULT_A; v *= hc; v ^= v >> 16; return v;
  };
  auto mix = [&](uint32_t x, uint32_t y) -> uint32_t {
    uint32_t r = x * MIX_L - y * MIX_R; r ^= r >> 16; return r;
  };
  for (int i = 0; i < 4; ++i) pool[i] = hashmix(0u);
  for (int s = 0; s < 4; ++s)
    for (int d = 0; d < 4; ++d)
      if (s != d) pool[d] = mix(pool[d], hashmix(pool[s]));
  uint32_t hb = INIT_B;
  uint32_t w[8];
  for (int i = 0; i < 8; ++i) {
    uint32_t dv = pool[i & 3];
    dv ^= hb; hb *= MULT_B; dv *= hb; dv ^= dv >> 16;
    w[i] = dv;
  }
  uint64_t v64[4];
  for (int i = 0; i < 4; ++i) v64[i] = (uint64_t)w[2 * i] | ((uint64_t)w[2 * i + 1] << 32);
  __uint128_t initstate = (((__uint128_t)v64[0]) << 64) | v64[1];
  __uint128_t initseq   = (((__uint128_t)v64[2]) << 64) | v64[3];
  g.inc = (initseq << 1) | 1;
  g.state = 0; g.has_uint32 = false; g.uinteger = 0;
  g.step();
  g.state += initstate;
  g.step();
}

static uint32_t lemire32(Pcg64& g, uint32_t rng) {
  if (rng == 0) return 0;
  const uint32_t rng_excl = rng + 1u;
  uint64_t m = (uint64_t)g.next32() * (uint64_t)rng_excl;
  uint32_t leftover = (uint32_t)m;
  if (leftover < rng_excl) {
    const uint32_t threshold = (0xFFFFFFFFu - rng) % rng_excl;
    while (leftover < threshold) {
      m = (uint64_t)g.next32() * (uint64_t)rng_excl;
      leftover = (uint32_t)m;
    }
  }
  return (uint32_t)(m >> 32);
}

static void choice3(Pcg64& g, int pop, int64_t out[3]) {
  uint64_t hset[4] = {~0ull, ~0ull, ~0ull, ~0ull};
  const uint64_t mask = 3;
  for (int j = pop - 3; j < pop; ++j) {
    uint64_t val = (uint64_t)lemire32(g, (uint32_t)j);
    uint64_t loc = val & mask;
    while (hset[loc] != ~0ull && hset[loc] != val) loc = (loc + 1) & mask;
    if (hset[loc] == ~0ull) {
      hset[loc] = val;
      out[j - pop + 3] = (int64_t)val;
    } else {
      loc = (uint64_t)j & mask;
      while (hset[loc] != ~0ull) loc = (loc + 1) & mask;
      hset[loc] = (uint64_t)j;
      out[j - pop + 3] = (int64_t)j;
    }
  }
  for (int i = 2; i >= 1; --i) {
    int j = (int)lemire32(g, (uint32_t)i);
    int64_t t = out[i]; out[i] = out[j]; out[j] = t;
  }
}

} // namespace nprng

static int all_combos(int s, int combos[80][8]) {
  int c[8];
  for (int i = 0; i < s; ++i) c[i] = i;
  int cnt = 0;
  while (true) {
    for (int i = 0; i < s; ++i) combos[cnt][i] = c[i];
    ++cnt;
    int i = s - 1;
    while (i >= 0 && c[i] == 8 - s + i) --i;
    if (i < 0) break;
    ++c[i];
    for (int j = i + 1; j < s; ++j) c[j] = c[j - 1] + 1;
  }
  return cnt;
}

// ===========================================================================
// Common defs
// ===========================================================================
#define NREL_MAX 19
#define MDIM 4096
#define NB   256
#define NC   400

typedef __attribute__((ext_vector_type(8))) short bf16x8;
typedef __attribute__((ext_vector_type(4))) float f32x4;

__device__ __forceinline__ uint16_t f2bf(float f) {
  uint32_t u = __builtin_bit_cast(uint32_t, f);
  u += 0x7FFFu + ((u >> 16) & 1u);   // RNE
  return (uint16_t)(u >> 16);
}

__device__ __forceinline__ void gload_lds16(const void* g, void* l) {
  __builtin_amdgcn_global_load_lds(
      (const __attribute__((address_space(1))) unsigned int*)g,
      (__attribute__((address_space(3))) unsigned int*)l, 16, 0, 0);
}

// ===========================================================================
// conversions (fast path)
// ===========================================================================
__global__ __launch_bounds__(256) void conv_x_kernel(
    const float* __restrict__ x, uint16_t* __restrict__ xr, int n8)
{
  int i = blockIdx.x * 256 + threadIdx.x;
  const int stride = gridDim.x * 256;
  for (; i < n8; i += stride) {
    const float4 a = ((const float4*)x)[2 * i];
    const float4 b = ((const float4*)x)[2 * i + 1];
    uint32_t p0 = (uint32_t)f2bf(fmaxf(a.x, 0.f)) | ((uint32_t)f2bf(fmaxf(a.y, 0.f)) << 16);
    uint32_t p1 = (uint32_t)f2bf(fmaxf(a.z, 0.f)) | ((uint32_t)f2bf(fmaxf(a.w, 0.f)) << 16);
    uint32_t p2 = (uint32_t)f2bf(fmaxf(b.x, 0.f)) | ((uint32_t)f2bf(fmaxf(b.y, 0.f)) << 16);
    uint32_t p3 = (uint32_t)f2bf(fmaxf(b.z, 0.f)) | ((uint32_t)f2bf(fmaxf(b.w, 0.f)) << 16);
    ((uint4*)xr)[i] = make_uint4(p0, p1, p2, p3);
  }
}

struct ConvTArgs { const float* src[7]; uint16_t* dst[7]; int K[7]; };

__global__ __launch_bounds__(256) void conv_wT_kernel(ConvTArgs a) {
  const int g = blockIdx.z;
  const int K = a.K[g];
  const int k0 = blockIdx.x * 32;
  if (k0 >= K) return;
  const int n0 = blockIdx.y * 32;
  __shared__ float t[32][33];
  const int tr = threadIdx.x >> 5;
  const int tc = threadIdx.x & 31;
  const float* src = a.src[g];
#pragma unroll
  for (int i = 0; i < 4; ++i) {
    const int r = tr + i * 8;
    t[r][tc] = src[(size_t)(k0 + r) * NB + n0 + tc];
  }
  __syncthreads();
  uint16_t* dst = a.dst[g];
#pragma unroll
  for (int i = 0; i < 4; ++i) {
    const int r = tr + i * 8;
    dst[(size_t)(n0 + r) * K + k0 + tc] = f2bf(t[tc][r]);
  }
}

struct G1F {
  const uint16_t* w1T[NREL_MAX];
  const float*    b1[NREL_MAX];
  unsigned char frames[NREL_MAX][8];
  unsigned char scale[NREL_MAX];
};
struct G2F {
  const uint16_t* w2T[NREL_MAX];
  const float*    b2[NREL_MAX];
};

// ===========================================================================
// GEMM1: 8-phase 256x256 schedule (T2+T3+T4+T5 per m201-style template).
//   BM=BN=256, BK=64, 512 thr = 8 waves (2M x 4N), per-wave out 128x64.
//   LDS = ring of 8 regions x 16KB (A/B x k-half x dbuf) = 128 KiB.
//   Half-tile order h: 4kt+{0:A-kh0, 1:B-kh0, 2:A-kh1, 3:B-kh1}; region h&7.
//   Per phase: ds-reads, stage 1 half-tile (2 gload_lds/thread), barrier,
//   setprio(1) 16 MFMA setprio(0), [counted vmcnt at p3], barrier.
//   Swizzle: kb ^= (row&3)<<4 on pre-swizzled global src AND ds_read (rule 21).
// ===========================================================================
__global__ __launch_bounds__(512, 2) void gemm1_8p(
    const uint16_t* __restrict__ xr,   // [4096][8][1024] bf16, relu applied
    uint16_t* __restrict__ h1,         // [zc][4096][256] bf16
    G1F args, int zbase)
{
  __shared__ __align__(16) uint16_t lds[65536];   // 128 KiB
  const int zl  = blockIdx.y;
  const int rel = zbase + zl;
  const int m0  = blockIdx.x << 8;
  const int scale = (int)args.scale[rel];
  const int NT  = scale << 4;          // K/64
  const int K   = scale << 10;
  const uint16_t* __restrict__ w1T = args.w1T[rel];
  const float* __restrict__ b1p = args.b1[rel];

  // hoist frames into a register (no kernarg traffic inside K-loop)
  uint64_t fru = 0;
#pragma unroll
  for (int j = 0; j < 8; ++j)
    fru |= ((uint64_t)args.frames[rel][j]) << (8 * j);

  const int tid  = threadIdx.x;
  const int l    = tid & 63;
  const int w    = tid >> 6;
  const int wm   = w >> 2;        // 0..1
  const int wn   = w & 3;         // 0..3
  const int lrow = l & 15;
  const int lk16 = (l >> 4) << 4; // byte offset of lane's 16B k-chunk

  auto STAGE = [&](int h) {
    const int kt = h >> 2, kh = (h >> 1) & 1, isB = h & 1;
    const int reg = (h & 7) << 14;
    const int fr = (int)((fru >> ((kt >> 4) << 3)) & 255);
    const int kbaseA = (fr << 10) + ((kt & 15) << 6) + (kh << 5);  // elems
    const int kbaseB = (kt << 6) + (kh << 5);                      // elems
#pragma unroll
    for (int j = 0; j < 2; ++j) {
      const int s = ((j << 9) + tid) << 4;         // dest byte in region
      const int row = s >> 6;                      // 0..255
      const int kb = (s & 63) ^ ((row & 3) << 4);  // pre-swizzled source
      const uint16_t* g;
      if (!isB) g = xr + (size_t)(m0 + row) * 8192 + kbaseA + (kb >> 1);
      else      g = w1T + (size_t)row * K + kbaseB + (kb >> 1);
      gload_lds16(g, (char*)lds + reg + (j << 13) + ((tid >> 6) << 10));
    }
  };
  auto LDA = [&](int reg, int rf) -> bf16x8 {
    const int row = (wm << 7) + (rf << 4) + lrow;
    const int kb = lk16 ^ ((row & 3) << 4);
    return *(const bf16x8*)((const char*)lds + reg + (row << 6) + kb);
  };
  auto LDB = [&](int reg, int cq, int cf) -> bf16x8 {
    const int col = (wn << 6) + (cq << 5) + (cf << 4) + lrow;
    const int kb = lk16 ^ ((col & 3) << 4);
    return *(const bf16x8*)((const char*)lds + reg + (col << 6) + kb);
  };

  f32x4 acc[8][4] = {};

  // ---- prologue: drain residual vmem, prefetch 7 half-tiles
  asm volatile("s_waitcnt vmcnt(0)" ::: "memory");
  STAGE(0); STAGE(1); STAGE(2); STAGE(3);
  asm volatile("s_waitcnt vmcnt(4)" ::: "memory");
  STAGE(4); STAGE(5); STAGE(6);
  asm volatile("s_waitcnt vmcnt(6)" ::: "memory");
  asm volatile("s_barrier" ::: "memory");

  const int HTOT = NT << 2;
  for (int kt = 0; kt < NT; ++kt) {
    const int h0 = kt << 2;
    const int regA0 = ((h0 + 0) & 7) << 14;
    const int regB0 = ((h0 + 1) & 7) << 14;
    const int regA1 = ((h0 + 2) & 7) << 14;
    const int regB1 = ((h0 + 3) & 7) << 14;
    bf16x8 af[8], bv[2];

    // ---------- phase 0: kh0, cols 0-31 ----------
#pragma unroll
    for (int rf = 0; rf < 8; ++rf) af[rf] = LDA(regA0, rf);
    bv[0] = LDB(regB0, 0, 0); bv[1] = LDB(regB0, 0, 1);
    if (h0 + 7 < HTOT) STAGE(h0 + 7);
    asm volatile("s_barrier" ::: "memory");
    __builtin_amdgcn_sched_barrier(0);
    __builtin_amdgcn_s_setprio(1);
#pragma unroll
    for (int rf = 0; rf < 8; ++rf) {
      acc[rf][0] = __builtin_amdgcn_mfma_f32_16x16x32_bf16(af[rf], bv[0], acc[rf][0], 0, 0, 0);
      acc[rf][1] = __builtin_amdgcn_mfma_f32_16x16x32_bf16(af[rf], bv[1], acc[rf][1], 0, 0, 0);
    }
    __builtin_amdgcn_s_setprio(0);
    asm volatile("s_barrier" ::: "memory");

    // ---------- phase 1: kh0, cols 32-63 ----------
    bv[0] = LDB(regB0, 1, 0); bv[1] = LDB(regB0, 1, 1);
    if (h0 + 8 < HTOT) STAGE(h0 + 8);
    asm volatile("s_barrier" ::: "memory");
    __builtin_amdgcn_sched_barrier(0);
    __builtin_amdgcn_s_setprio(1);
#pragma unroll
    for (int rf = 0; rf < 8; ++rf) {
      acc[rf][2] = __builtin_amdgcn_mfma_f32_16x16x32_bf16(af[rf], bv[0], acc[rf][2], 0, 0, 0);
      acc[rf][3] = __builtin_amdgcn_mfma_f32_16x16x32_bf16(af[rf], bv[1], acc[rf][3], 0, 0, 0);
    }
    __builtin_amdgcn_s_setprio(0);
    asm volatile("s_barrier" ::: "memory");

    // ---------- phase 2: kh1, cols 0-31 ----------
#pragma unroll
    for (int rf = 0; rf < 8; ++rf) af[rf] = LDA(regA1, rf);
    bv[0] = LDB(regB1, 0, 0); bv[1] = LDB(regB1, 0, 1);
    if (h0 + 9 < HTOT) STAGE(h0 + 9);
    asm volatile("s_barrier" ::: "memory");
    __builtin_amdgcn_sched_barrier(0);
    __builtin_amdgcn_s_setprio(1);
#pragma unroll
    for (int rf = 0; rf < 8; ++rf) {
      acc[rf][0] = __builtin_amdgcn_mfma_f32_16x16x32_bf16(af[rf], bv[0], acc[rf][0], 0, 0, 0);
      acc[rf][1] = __builtin_amdgcn_mfma_f32_16x16x32_bf16(af[rf], bv[1], acc[rf][1], 0, 0, 0);
    }
    __builtin_amdgcn_s_setprio(0);
    asm volatile("s_barrier" ::: "memory");

    // ---------- phase 3: kh1, cols 32-63 ----------
    bv[0] = LDB(regB1, 1, 0); bv[1] = LDB(regB1, 1, 1);
    if (h0 + 10 < HTOT) STAGE(h0 + 10);
    asm volatile("s_barrier" ::: "memory");
    __builtin_amdgcn_sched_barrier(0);
    __builtin_amdgcn_s_setprio(1);
#pragma unroll
    for (int rf = 0; rf < 8; ++rf) {
      acc[rf][2] = __builtin_amdgcn_mfma_f32_16x16x32_bf16(af[rf], bv[0], acc[rf][2], 0, 0, 0);
      acc[rf][3] = __builtin_amdgcn_mfma_f32_16x16x32_bf16(af[rf], bv[1], acc[rf][3], 0, 0, 0);
    }
    __builtin_amdgcn_s_setprio(0);
    // counted vmcnt ONCE per K-tile; drain fully before the last tile
    if (kt == NT - 2)      asm volatile("s_waitcnt vmcnt(0)" ::: "memory");
    else if (kt < NT - 2)  asm volatile("s_waitcnt vmcnt(6)" ::: "memory");
    asm volatile("s_barrier" ::: "memory");
  }

  // ---- epilogue: bias + relu + bf16, write h1 ----
  float b1v[4];
#pragma unroll
  for (int c = 0; c < 4; ++c) b1v[c] = b1p[(wn << 6) + (c << 4) + lrow];
  const int rsub = (l >> 4) << 2;
#pragma unroll
  for (int rf = 0; rf < 8; ++rf) {
#pragma unroll
    for (int q = 0; q < 4; ++q) {
      const int row = m0 + (wm << 7) + (rf << 4) + rsub + q;
      uint16_t* hp = h1 + ((size_t)zl * MDIM + row) * NB + (wn << 6) + lrow;
#pragma unroll
      for (int c = 0; c < 4; ++c)
        hp[c << 4] = f2bf(fmaxf(acc[rf][c][q] + b1v[c], 0.f));
    }
  }
}

// ===========================================================================
// GEMM2: partials[g] (+)= sum_{rel in group g} relu(h1_rel * w2 + b2).
// 64x64 tile, BK=32, 4 waves, grid.z = ngrp rel-groups (no atomics).
// ===========================================================================
__global__ __launch_bounds__(256) void gemm2_mfma(
    const uint16_t* __restrict__ h1, float* __restrict__ partials,
    G2F args, int zbase, int zcount, int gsz, int is_first)
{
  __shared__ __align__(16) uint16_t sA[64 * 32];
  __shared__ __align__(16) uint16_t sB[64 * 32];
  const int m0 = blockIdx.x * 64;
  const int n0 = blockIdx.y * 64;
  const int grp = blockIdx.z;
  const int z0 = grp * gsz;
  int z1 = z0 + gsz; if (z1 > zcount) z1 = zcount;
  float* outb = partials + (size_t)grp * MDIM * NB;

  const int tid  = threadIdx.x;
  const int l    = tid & 63;
  const int w    = tid >> 6;
  const int wm   = w >> 1, wn = w & 1;
  const int lcol = l & 15;
  const int kgrp = (l >> 4) << 3;
  const int srow = tid >> 2;
  const int sko  = (tid & 3) << 3;
  const int ldsoff = (tid >> 6) << 10;

  float tot[2][2][4] = {};

  for (int zl = z0; zl < z1; ++zl) {
    const int rel = zbase + zl;
    const uint16_t* __restrict__ w2T = args.w2T[rel];
    const uint16_t* ha = h1 + ((size_t)zl * MDIM + m0 + srow) * NB + sko;
    const uint16_t* wb = w2T + (size_t)(n0 + srow) * NB + sko;
    f32x4 acc[2][2] = {};
    for (int k0 = 0; k0 < NB; k0 += 32) {
      gload_lds16(ha + k0, (char*)sA + ldsoff);
      gload_lds16(wb + k0, (char*)sB + ldsoff);
      asm volatile("s_waitcnt vmcnt(0)" ::: "memory");
      __syncthreads();
      bf16x8 af[2], bv[2];
#pragma unroll
      for (int i = 0; i < 2; ++i) {
        af[i] = *(const bf16x8*)((const char*)sA + (((wm << 5) + (i << 4) + lcol) << 6) + (kgrp << 1));
        bv[i] = *(const bf16x8*)((const char*)sB + (((wn << 5) + (i << 4) + lcol) << 6) + (kgrp << 1));
      }
#pragma unroll
      for (int i = 0; i < 2; ++i)
#pragma unroll
        for (int j = 0; j < 2; ++j)
          acc[i][j] = __builtin_amdgcn_mfma_f32_16x16x32_bf16(af[i], bv[j], acc[i][j], 0, 0, 0);
      __syncthreads();
    }
    const float* b2 = args.b2[rel];
    float b2v[2];
#pragma unroll
    for (int j = 0; j < 2; ++j) b2v[j] = b2[n0 + (wn << 5) + (j << 4) + lcol];
#pragma unroll
    for (int i = 0; i < 2; ++i)
#pragma unroll
      for (int j = 0; j < 2; ++j)
#pragma unroll
        for (int q = 0; q < 4; ++q)
          tot[i][j][q] += fmaxf(acc[i][j][q] + b2v[j], 0.f);
  }

  const int orow = (l >> 4) << 2;
#pragma unroll
  for (int i = 0; i < 2; ++i) {
#pragma unroll
    for (int q = 0; q < 4; ++q) {
      const int row = m0 + (wm << 5) + (i << 4) + orow + q;
      float* ap = outb + (size_t)row * NB + n0 + (wn << 5) + lcol;
#pragma unroll
      for (int j = 0; j < 2; ++j) {
        float v = tot[i][j][q];
        if (!is_first) v += ap[j << 4];
        ap[j << 4] = v;
      }
    }
  }
}

__global__ __launch_bounds__(256) void reduce4_kernel(
    const float* __restrict__ p, float* __restrict__ accb)
{
  const int i = blockIdx.x * 256 + threadIdx.x;           // float4 index
  const size_t Q = (size_t)MDIM * NB / 4;                 // 262144
  const float4* p4 = (const float4*)p;
  float4 a = p4[i], b = p4[i + Q], c = p4[i + 2 * Q], d = p4[i + 3 * Q];
  float4 o;
  o.x = a.x + b.x + c.x + d.x;
  o.y = a.y + b.y + c.y + d.y;
  o.z = a.z + b.z + c.z + d.z;
  o.w = a.w + b.w + c.w + d.w;
  ((float4*)accb)[i] = o;
}

// ===========================================================================
// FALLBACK PATH (round-1 fp32 SIMT, known-good) + shared GEMM3
// ===========================================================================
#define MTILE 64
#define NTILE 64
#define KTILE 32
#define LSTR  68

struct G1Args {
  const float* w1[NREL_MAX];
  const float* b1[NREL_MAX];
  unsigned char frames[NREL_MAX][8];
  unsigned char scale[NREL_MAX];
};
struct G2Args {
  const float* w2[NREL_MAX];
  const float* b2[NREL_MAX];
};

__global__ __launch_bounds__(256) void gemm1_kernel(
    const float* __restrict__ x, float* __restrict__ h1, G1Args args, int zbase)
{
  const int zl  = blockIdx.z;
  const int rel = zbase + zl;
  const int m0  = blockIdx.x * MTILE;
  const int n0  = blockIdx.y * NTILE;
  const int K   = ((int)args.scale[rel]) << 10;
  const float* __restrict__ w1 = args.w1[rel];

  __shared__ float As[KTILE][LSTR];
  __shared__ float Bs[KTILE][LSTR];

  const int tid = threadIdx.x;
  const int tx = tid & 15, ty = tid >> 4;
  const int lkA = tid & 31, lmA = tid >> 5;
  const int lnB = tid & 63, lkB = tid >> 6;

  float acc[4][4] = {};

  for (int k0 = 0; k0 < K; k0 += KTILE) {
    const int fr = (int)args.frames[rel][k0 >> 10];
    const float* xp = x + (size_t)m0 * 8192 + (size_t)fr * 1024 + (k0 & 1023) + lkA;
#pragma unroll
    for (int r = 0; r < 8; ++r) {
      float v = xp[(size_t)(lmA + r * 8) * 8192];
      As[lkA][lmA + r * 8] = fmaxf(v, 0.f);
    }
    const float* wp = w1 + (size_t)(k0 + lkB) * NB + n0 + lnB;
#pragma unroll
    for (int r = 0; r < 8; ++r)
      Bs[lkB + r * 4][lnB] = wp[(size_t)r * 4 * NB];
    __syncthreads();
#pragma unroll
    for (int k = 0; k < KTILE; ++k) {
      const float4 av = *(const float4*)&As[k][ty << 2];
      const float4 bvv = *(const float4*)&Bs[k][tx << 2];
      const float ar[4] = {av.x, av.y, av.z, av.w};
      const float br[4] = {bvv.x, bvv.y, bvv.z, bvv.w};
#pragma unroll
      for (int r = 0; r < 4; ++r)
#pragma unroll
        for (int c = 0; c < 4; ++c)
          acc[r][c] = fmaf(ar[r], br[c], acc[r][c]);
    }
    __syncthreads();
  }

  const float* b1p = args.b1[rel] + n0 + (tx << 2);
  const float4 bias = {b1p[0], b1p[1], b1p[2], b1p[3]};
  float* outp = h1 + ((size_t)zl * MDIM + m0 + (ty << 2)) * NB + n0 + (tx << 2);
#pragma unroll
  for (int r = 0; r < 4; ++r) {
    float4 o;
    o.x = fmaxf(acc[r][0] + bias.x, 0.f);
    o.y = fmaxf(acc[r][1] + bias.y, 0.f);
    o.z = fmaxf(acc[r][2] + bias.z, 0.f);
    o.w = fmaxf(acc[r][3] + bias.w, 0.f);
    *(float4*)(outp + (size_t)r * NB) = o;
  }
}

__global__ __launch_bounds__(256) void gemm2_kernel(
    const float* __restrict__ h1, float* __restrict__ accb,
    G2Args args, int zbase, int zcount, int is_first)
{
  const int m0 = blockIdx.x * MTILE;
  const int n0 = blockIdx.y * NTILE;

  __shared__ float As[KTILE][LSTR];
  __shared__ float Bs[KTILE][LSTR];

  const int tid = threadIdx.x;
  const int tx = tid & 15, ty = tid >> 4;
  const int lkA = tid & 31, lmA = tid >> 5;
  const int lnB = tid & 63, lkB = tid >> 6;

  float total[4][4] = {};

  for (int zl = 0; zl < zcount; ++zl) {
    const int rel = zbase + zl;
    const float* __restrict__ w2 = args.w2[rel];
    float acc[4][4] = {};
    for (int k0 = 0; k0 < NB; k0 += KTILE) {
      const float* hp = h1 + ((size_t)zl * MDIM + m0) * NB + k0 + lkA;
#pragma unroll
      for (int r = 0; r < 8; ++r)
        As[lkA][lmA + r * 8] = hp[(size_t)(lmA + r * 8) * NB];
      const float* wp = w2 + (size_t)(k0 + lkB) * NB + n0 + lnB;
#pragma unroll
      for (int r = 0; r < 8; ++r)
        Bs[lkB + r * 4][lnB] = wp[(size_t)r * 4 * NB];
      __syncthreads();
#pragma unroll
      for (int k = 0; k < KTILE; ++k) {
        const float4 av = *(const float4*)&As[k][ty << 2];
        const float4 bvv = *(const float4*)&Bs[k][tx << 2];
        const float ar[4] = {av.x, av.y, av.z, av.w};
        const float br[4] = {bvv.x, bvv.y, bvv.z, bvv.w};
#pragma unroll
        for (int r = 0; r < 4; ++r)
#pragma unroll
          for (int c = 0; c < 4; ++c)
            acc[r][c] = fmaf(ar[r], br[c], acc[r][c]);
      }
      __syncthreads();
    }
    const float* b2p = args.b2[rel] + n0 + (tx << 2);
    const float b2v[4] = {b2p[0], b2p[1], b2p[2], b2p[3]};
#pragma unroll
    for (int r = 0; r < 4; ++r)
#pragma unroll
      for (int c = 0; c < 4; ++c)
        total[r][c] += fmaxf(acc[r][c] + b2v[c], 0.f);
  }

  float* outp = accb + (size_t)(m0 + (ty << 2)) * NB + n0 + (tx << 2);
#pragma unroll
  for (int r = 0; r < 4; ++r) {
    float4 cur;
    if (is_first) { cur.x = cur.y = cur.z = cur.w = 0.f; }
    else          { cur = *(float4*)(outp + (size_t)r * NB); }
    cur.x += total[r][0];
    cur.y += total[r][1];
    cur.z += total[r][2];
    cur.w += total[r][3];
    *(float4*)(outp + (size_t)r * NB) = cur;
  }
}

__global__ __launch_bounds__(256) void gemm3_kernel(
    const float* __restrict__ accb, const float* __restrict__ wc,
    const float* __restrict__ bc, float* __restrict__ out)
{
  const int m0 = blockIdx.x * MTILE;
  const int n0 = blockIdx.y * NTILE;

  __shared__ float As[KTILE][LSTR];
  __shared__ float Bs[KTILE][LSTR];

  const int tid = threadIdx.x;
  const int tx = tid & 15, ty = tid >> 4;
  const int lkA = tid & 31, lmA = tid >> 5;
  const int lnB = tid & 63, lkB = tid >> 6;

  float acc[4][4] = {};

  for (int k0 = 0; k0 < NB; k0 += KTILE) {
    const float* hp = accb + (size_t)m0 * NB + k0 + lkA;
#pragma unroll
    for (int r = 0; r < 8; ++r)
      As[lkA][lmA + r * 8] = hp[(size_t)(lmA + r * 8) * NB];
    const int col = n0 + lnB;
#pragma unroll
    for (int r = 0; r < 8; ++r) {
      float v = 0.f;
      if (col < NC) v = wc[(size_t)(k0 + lkB + r * 4) * NC + col];
      Bs[lkB + r * 4][lnB] = v;
    }
    __syncthreads();
#pragma unroll
    for (int k = 0; k < KTILE; ++k) {
      const float4 av = *(const float4*)&As[k][ty << 2];
      const float4 bvv = *(const float4*)&Bs[k][tx << 2];
      const float ar[4] = {av.x, av.y, av.z, av.w};
      const float br[4] = {bvv.x, bvv.y, bvv.z, bvv.w};
#pragma unroll
      for (int r = 0; r < 4; ++r)
#pragma unroll
        for (int c = 0; c < 4; ++c)
          acc[r][c] = fmaf(ar[r], br[c], acc[r][c]);
    }
    __syncthreads();
  }

#pragma unroll
  for (int r = 0; r < 4; ++r) {
    const int row = m0 + (ty << 2) + r;
#pragma unroll
    for (int c = 0; c < 4; ++c) {
      const int col = n0 + (tx << 2) + c;
      if (col < NC)
        out[(size_t)row * NC + col] = fmaxf(acc[r][c] + bc[col], 0.f);
    }
  }
}

// ===========================================================================
extern "C" void kernel_launch(void* const* d_in, const int* in_sizes, int n_in,
                              void* d_out, int out_size, void* d_ws, size_t ws_size,
                              hipStream_t stream) {
  {
    nprng::Pcg64 chk; nprng::make_default_rng0(chk);
    double r0 = (double)(chk.next64() >> 11) * (1.0 / 9007199254740992.0);
    if (!(r0 > 0.6369616872 && r0 < 0.6369616874))
      fprintf(stderr, "[kernel] WARNING: PCG64 self-check failed: %.17g\n", r0);
  }

  // ---- build REL
  int rel_frames[NREL_MAX][8];
  int rel_scale[NREL_MAX];
  int rel_group[NREL_MAX];
  int n_rel = 0;
  for (int j = 0; j < 8; ++j) rel_frames[0][j] = j;
  rel_scale[0] = 8; rel_group[0] = 0; n_rel = 1;

  nprng::Pcg64 rng; nprng::make_default_rng0(rng);
  for (int gi = 1; gi <= 6; ++gi) {
    const int scale = 8 - gi;
    int combos[80][8];
    const int pop = all_combos(scale, combos);
    int64_t idx[3];
    nprng::choice3(rng, pop, idx);
    for (int t = 0; t < 3; ++t) {
      for (int j = 0; j < 8; ++j) rel_frames[n_rel][j] = (j < scale) ? combos[idx[t]][j] : 0;
      rel_scale[n_rel] = scale;
      rel_group[n_rel] = gi;
      ++n_rel;
    }
  }

  const float* x  = (const float*)d_in[0];
  const float* wc = (const float*)d_in[29];
  const float* bc = (const float*)d_in[30];

  // ---- ws layout (fast path): acc | xr | w1T | w2T | [parts] | h1
  const size_t ACC_B   = (size_t)MDIM * NB * 4;                 // 4 MiB
  const size_t XR_B    = (size_t)MDIM * 8 * 1024 * 2;           // 64 MiB
  const size_t W1T_B   = (size_t)35 * 1024 * NB * 2;            // 17.5 MiB
  const size_t W2T_B   = (size_t)7 * NB * NB * 2;               // 0.875 MiB
  const size_t H1REL_B = (size_t)MDIM * NB * 2;                 // 2 MiB / rel
  const size_t off_xr  = ACC_B;
  const size_t off_w1t = off_xr + XR_B;
  const size_t off_w2t = off_w1t + W1T_B;
  const size_t base    = off_w2t + W2T_B;                       // 86.375 MiB

  float* accb = (float*)d_ws;

  // adaptive gemm2 group count: 4 partial buffers if they fit, else 1 (accb)
  int ngrp;
  size_t off_part, off_h1;
  if (ws_size >= base + 4 * ACC_B + H1REL_B)      { ngrp = 4; off_part = base; off_h1 = base + 4 * ACC_B; }
  else if (ws_size >= base + H1REL_B)             { ngrp = 1; off_part = 0;    off_h1 = base; }
  else                                            { ngrp = 0; off_part = 0;    off_h1 = 0; }

  if (ngrp > 0) {
    // ---------------- FAST PATH (bf16 MFMA) ----------------
    float*    parts = (ngrp == 4) ? (float*)((char*)d_ws + off_part) : accb;
    uint16_t* xr = (uint16_t*)((char*)d_ws + off_xr);
    uint16_t* h1 = (uint16_t*)((char*)d_ws + off_h1);
    int zcap = (int)((ws_size - off_h1) / H1REL_B);
    if (zcap > n_rel) zcap = n_rel;

    uint16_t* w1t_g[7];
    size_t o = off_w1t;
    for (int g = 0; g < 7; ++g) {
      w1t_g[g] = (uint16_t*)((char*)d_ws + o);
      o += (size_t)(8 - g) * 1024 * NB * 2;
    }
    uint16_t* w2t_g[7];
    for (int g = 0; g < 7; ++g)
      w2t_g[g] = (uint16_t*)((char*)d_ws + off_w2t + (size_t)g * NB * NB * 2);

    conv_x_kernel<<<4096, 256, 0, stream>>>(x, xr, (int)(MDIM * 8 * 1024 / 8));
    ConvTArgs c1, c2;
    for (int g = 0; g < 7; ++g) {
      c1.src[g] = (const float*)d_in[1 + 4 * g];
      c1.dst[g] = w1t_g[g];
      c1.K[g]   = (8 - g) * 1024;
      c2.src[g] = (const float*)d_in[3 + 4 * g];
      c2.dst[g] = w2t_g[g];
      c2.K[g]   = NB;
    }
    conv_wT_kernel<<<dim3(256, 8, 7), 256, 0, stream>>>(c1);
    conv_wT_kernel<<<dim3(8, 8, 7), 256, 0, stream>>>(c2);

    G1F g1; G2F g2;
    memset(&g1, 0, sizeof(g1)); memset(&g2, 0, sizeof(g2));
    for (int r = 0; r < n_rel; ++r) {
      const int gi = rel_group[r];
      g1.w1T[r] = w1t_g[gi];
      g1.b1[r]  = (const float*)d_in[2 + 4 * gi];
      g2.w2T[r] = w2t_g[gi];
      g2.b2[r]  = (const float*)d_in[4 + 4 * gi];
      for (int j = 0; j < 8; ++j) g1.frames[r][j] = (unsigned char)rel_frames[r][j];
      g1.scale[r] = (unsigned char)rel_scale[r];
    }

    int zbase = 0, first = 1;
    while (zbase < n_rel) {
      const int zc = (n_rel - zbase < zcap) ? (n_rel - zbase) : zcap;
      gemm1_8p<<<dim3(MDIM / 256, zc), 512, 0, stream>>>(xr, h1, g1, zbase);
      const int gsz = (zc + ngrp - 1) / ngrp;
      gemm2_mfma<<<dim3(MDIM / 64, NB / 64, ngrp), 256, 0, stream>>>(
          h1, parts, g2, zbase, zc, gsz, first);
      first = 0;
      zbase += zc;
    }
    if (ngrp == 4)
      reduce4_kernel<<<dim3(MDIM * NB / 4 / 256), 256, 0, stream>>>(parts, accb);
  } else {
    // ---------------- FALLBACK (fp32 SIMT, round-1) ----------------
    G1Args g1; G2Args g2;
    memset(&g1, 0, sizeof(g1)); memset(&g2, 0, sizeof(g2));
    for (int r = 0; r < n_rel; ++r) {
      const int gi = rel_group[r];
      g1.w1[r] = (const float*)d_in[1 + 4 * gi];
      g1.b1[r] = (const float*)d_in[2 + 4 * gi];
      g2.w2[r] = (const float*)d_in[3 + 4 * gi];
      g2.b2[r] = (const float*)d_in[4 + 4 * gi];
      for (int j = 0; j < 8; ++j) g1.frames[r][j] = (unsigned char)rel_frames[r][j];
      g1.scale[r] = (unsigned char)rel_scale[r];
    }
    const size_t ACC_ELEMS = (size_t)MDIM * NB;
    float* h1f = (float*)d_ws + ACC_ELEMS;
    size_t avail = ws_size / 4;
    int zcap = 1;
    if (avail > ACC_ELEMS) {
      size_t cap = (avail - ACC_ELEMS) / ACC_ELEMS;
      zcap = (int)(cap < (size_t)n_rel ? cap : (size_t)n_rel);
      if (zcap < 1) zcap = 1;
    }
    int zbase = 0, first = 1;
    while (zbase < n_rel) {
      const int zc = (n_rel - zbase < zcap) ? (n_rel - zbase) : zcap;
      gemm1_kernel<<<dim3(MDIM / MTILE, NB / NTILE, zc), 256, 0, stream>>>(x, h1f, g1, zbase);
      gemm2_kernel<<<dim3(MDIM / MTILE, NB / NTILE), 256, 0, stream>>>(h1f, accb, g2, zbase, zc, first);
      first = 0;
      zbase += zc;
    }
  }

  gemm3_kernel<<<dim3(MDIM / MTILE, (NC + NTILE - 1) / NTILE), 256, 0, stream>>>(
      accb, wc, bc, (float*)d_out);
}